// Round 9
// baseline (224.602 us; speedup 1.0000x reference)
//
#include <hip/hip_runtime.h>
#include <math.h>

#define FOURPI 12.566370614359172

typedef _Float16 f16x8 __attribute__((ext_vector_type(8)));
typedef float    f32x4 __attribute__((ext_vector_type(4)));

// R8 structure + LDS union + merged idx-copy tail blocks.
//  - Ylds [256 rows][40 halves] = 20 KB, per-wave partitioned (wave w owns
//    rows [64w, 64w+64)), NO __syncthreads anywhere -> waves free-run.
//  - All 4 mt A-fragment pairs pre-read into registers (proven neutral in
//    R5/R6 A/B), then per-wave Cbuf [16][68] floats (4352 B) ALIASES the
//    wave's own 5120 B Ylds slice -> total LDS 20 KB.
//  - launch_bounds(256,5): 5 blocks/CU (VGPR target ~102, live ~90).
//  - Store path unchanged (the proven one): MFMA -> Cbuf restage ->
//    1KB-contiguous float4 stores (64 lanes = 1 KB/instruction, full lines).
//  - Grid tail: blocks >= nb_main convert pair_indices int->float, 4 float4
//    per thread, coalesced; removes the second launch.
__global__ __launch_bounds__(256, 5) void sph_edge_kernel(
    const float* __restrict__ env,    // [N,2,3]
    const int4*  __restrict__ idx4,   // pair_indices as int32 x4
    const float* __restrict__ Kmat,   // [36,64]
    const float* __restrict__ bias,   // [64]
    float* __restrict__ out,          // [N,64] floats, then [N,2] as float
    int N, int n4, int nb_main)
{
    __shared__ __align__(16) _Float16 Ylds[256 * 40];   // 20 KB total

    const int tid  = threadIdx.x;

    // ---------------- tail blocks: pair_indices copy ----------------
    if ((int)blockIdx.x >= nb_main) {
        int tb = blockIdx.x - nb_main;
        float4* op = reinterpret_cast<float4*>(out + (size_t)N * 64);
        #pragma unroll
        for (int j = 0; j < 4; ++j) {
            int i4 = tb * 1024 + j * 256 + tid;
            if (i4 < n4) {
                int4 v = idx4[i4];
                op[i4] = make_float4((float)v.x, (float)v.y,
                                     (float)v.z, (float)v.w);
            }
        }
        return;
    }

    const int lane = tid & 63;
    const int w    = tid >> 6;
    const int g    = lane >> 4;   // 16-lane group 0..3
    const int c    = lane & 15;
    const int base = blockIdx.x * 256;
    const int valid = (N - base < 256) ? (N - base) : 256;

    // per-wave Cbuf aliases the wave's own Ylds slice (4352 B of 5120 B)
    float* Cbuf = reinterpret_cast<float*>(&Ylds[w * 64 * 40]);

    // ---- B fragments: lane holds B[k=kt*32+g*8+j][col=nt*16+c] ----
    f16x8 Bf[4][2];
    #pragma unroll
    for (int nt = 0; nt < 4; ++nt) {
        #pragma unroll
        for (int kt = 0; kt < 2; ++kt) {
            #pragma unroll
            for (int j = 0; j < 8; ++j) {
                int k = kt * 32 + g * 8 + j;
                float v = (k < 36) ? Kmat[k * 64 + nt * 16 + c] : 0.f;
                Bf[nt][kt][j] = (_Float16)v;
            }
        }
    }
    float biasv[4];
    #pragma unroll
    for (int nt = 0; nt < 4; ++nt) biasv[nt] = bias[nt * 16 + c];

    // ---------------- Phase 1: geometry + Y[36] ----------------
    float Y[36];
    if (tid < valid) {
        const float* p6 = env + (size_t)(base + tid) * 6;
        float2 v0 = *reinterpret_cast<const float2*>(p6);
        float2 v1 = *reinterpret_cast<const float2*>(p6 + 2);
        float2 v2 = *reinterpret_cast<const float2*>(p6 + 4);
        float px = v0.x, py = v0.y, pz = v1.x;
        float ex = v1.y, ey = v2.x, ez = v2.y;

        float dot_t = px*ex + py*ey + pz*ez;
        float cxv = py*ez - pz*ey;
        float cyv = pz*ex - px*ez;
        float czv = px*ey - py*ex;
        float cr2 = cxv*cxv + cyv*cyv + czv*czv;
        float cross_t = sqrtf(cr2);
        float r = sqrtf(dot_t*dot_t + cr2);
        float x = 1.f, s = 0.f;               // cos(theta), sin(theta)
        if (r > 0.f) { x = dot_t / r; s = cross_t / r; }

        float dp = ez * x;
        float cp = fabsf(x) * cross_t;
        float rp = sqrtf(dp*dp + cp*cp);
        float c1 = 1.f, s1 = 0.f;             // cos(phi), sin(phi)
        if (rp > 0.f) { c1 = dp / rp; s1 = cp / rp; }

        float tc = 2.f * c1;
        float cm1 = c1,            sm1 = s1;
        float cm2 = tc*cm1 - 1.f,  sm2 = tc*sm1;
        float cm3 = tc*cm2 - cm1,  sm3 = tc*sm2 - sm1;
        float cm4 = tc*cm3 - cm2,  sm4 = tc*sm3 - sm2;
        float cm5 = tc*cm4 - cm3,  sm5 = tc*sm4 - sm3;

        float s2 = s*s, s3 = s2*s, s4 = s2*s2, s5 = s4*s;
        float P10 = x;
        float P11 = -s;
        float P20 = 1.5f*x*x - 0.5f;
        float P21 = -3.f*x*s;
        float P22 = 3.f*s2;
        float P30 = (5.f*x*P20 - 2.f*P10) * (1.f/3.f);
        float P31 = (5.f*x*P21 - 3.f*P11) * 0.5f;
        float P32 = 5.f*x*P22;
        float P33 = -15.f*s3;
        float P40 = (7.f*x*P30 - 3.f*P20) * 0.25f;
        float P41 = (7.f*x*P31 - 4.f*P21) * (1.f/3.f);
        float P42 = (7.f*x*P32 - 5.f*P22) * 0.5f;
        float P43 = 7.f*x*P33;
        float P44 = 105.f*s4;
        float P50 = (9.f*x*P40 - 4.f*P30) * 0.2f;
        float P51 = (9.f*x*P41 - 5.f*P31) * 0.25f;
        float P52 = (9.f*x*P42 - 6.f*P32) * (1.f/3.f);
        float P53 = (9.f*x*P43 - 7.f*P33) * 0.5f;
        float P54 = 9.f*x*P44;
        float P55 = -945.f*s5;

        const float SQ2 = 1.4142135623730951f;
        const float K00 = (float)sqrt(1.0/FOURPI);
        const float K10 = (float)sqrt(3.0/FOURPI);
        const float K11 = (float)sqrt(3.0/FOURPI/2.0);
        const float K20 = (float)sqrt(5.0/FOURPI);
        const float K21 = (float)sqrt(5.0/FOURPI/6.0);
        const float K22 = (float)sqrt(5.0/FOURPI/24.0);
        const float K30 = (float)sqrt(7.0/FOURPI);
        const float K31 = (float)sqrt(7.0/FOURPI/12.0);
        const float K32 = (float)sqrt(7.0/FOURPI/120.0);
        const float K33 = (float)sqrt(7.0/FOURPI/720.0);
        const float K40 = (float)sqrt(9.0/FOURPI);
        const float K41 = (float)sqrt(9.0/FOURPI/20.0);
        const float K42 = (float)sqrt(9.0/FOURPI/360.0);
        const float K43 = (float)sqrt(9.0/FOURPI/5040.0);
        const float K44 = (float)sqrt(9.0/FOURPI/40320.0);
        const float K50 = (float)sqrt(11.0/FOURPI);
        const float K51 = (float)sqrt(11.0/FOURPI/30.0);
        const float K52 = (float)sqrt(11.0/FOURPI/840.0);
        const float K53 = (float)sqrt(11.0/FOURPI/20160.0);
        const float K54 = (float)sqrt(11.0/FOURPI/362880.0);
        const float K55 = (float)sqrt(11.0/FOURPI/3628800.0);

        Y[0]  = K00;
        Y[1]  = SQ2*K11*sm1*P11;
        Y[2]  = K10*P10;
        Y[3]  = SQ2*K11*cm1*P11;
        Y[4]  = SQ2*K22*sm2*P22;
        Y[5]  = SQ2*K21*sm1*P21;
        Y[6]  = K20*P20;
        Y[7]  = SQ2*K21*cm1*P21;
        Y[8]  = SQ2*K22*cm2*P22;
        Y[9]  = SQ2*K33*sm3*P33;
        Y[10] = SQ2*K32*sm2*P32;
        Y[11] = SQ2*K31*sm1*P31;
        Y[12] = K30*P30;
        Y[13] = SQ2*K31*cm1*P31;
        Y[14] = SQ2*K32*cm2*P32;
        Y[15] = SQ2*K33*cm3*P33;
        Y[16] = SQ2*K44*sm4*P44;
        Y[17] = SQ2*K43*sm3*P43;
        Y[18] = SQ2*K42*sm2*P42;
        Y[19] = SQ2*K41*sm1*P41;
        Y[20] = K40*P40;
        Y[21] = SQ2*K41*cm1*P41;
        Y[22] = SQ2*K42*cm2*P42;
        Y[23] = SQ2*K43*cm3*P43;
        Y[24] = SQ2*K44*cm4*P44;
        Y[25] = SQ2*K55*sm5*P55;
        Y[26] = SQ2*K54*sm4*P54;
        Y[27] = SQ2*K53*sm3*P53;
        Y[28] = SQ2*K52*sm2*P52;
        Y[29] = SQ2*K51*sm1*P51;
        Y[30] = K50*P50;
        Y[31] = SQ2*K51*cm1*P51;
        Y[32] = SQ2*K52*cm2*P52;
        Y[33] = SQ2*K53*cm3*P53;
        Y[34] = SQ2*K54*cm4*P54;
        Y[35] = SQ2*K55*cm5*P55;
    } else {
        #pragma unroll
        for (int i = 0; i < 36; ++i) Y[i] = 0.f;
    }

    // write own row: 40 halves (36 data + 4 zeros), 5 x b128
    {
        _Float16 yh[40];
        #pragma unroll
        for (int i = 0; i < 36; ++i) yh[i] = (_Float16)Y[i];
        #pragma unroll
        for (int i = 36; i < 40; ++i) yh[i] = (_Float16)0.f;
        f16x8* yr = reinterpret_cast<f16x8*>(&Ylds[tid * 40]);
        #pragma unroll
        for (int s5 = 0; s5 < 5; ++s5)
            yr[s5] = *reinterpret_cast<const f16x8*>(&yh[s5 * 8]);
    }
    __builtin_amdgcn_wave_barrier();
    asm volatile("s_waitcnt lgkmcnt(0)" ::: "memory");
    __builtin_amdgcn_sched_barrier(0);

    // -------- pre-read ALL A-fragments (wave-local), then Ylds slice is
    //          dead for this wave and Cbuf may alias it --------
    f16x8 a0[4], a1[4];
    #pragma unroll
    for (int mt = 0; mt < 4; ++mt) {
        const int row = w * 64 + mt * 16 + c;
        a0[mt] = *reinterpret_cast<const f16x8*>(&Ylds[row * 40 + g * 8]);
        f16x8 t = {};
        if (g == 0)
            t = *reinterpret_cast<const f16x8*>(&Ylds[row * 40 + 32]);
        a1[mt] = t;
    }
    __builtin_amdgcn_wave_barrier();
    asm volatile("s_waitcnt lgkmcnt(0)" ::: "memory");
    __builtin_amdgcn_sched_barrier(0);

    // ---------------- Phase 2+3: MFMA per 16-edge tile, restage, store ----
    #pragma unroll
    for (int mt = 0; mt < 4; ++mt) {
        f32x4 acc[4];
        #pragma unroll
        for (int nt = 0; nt < 4; ++nt) {
            f32x4 a = {biasv[nt], biasv[nt], biasv[nt], biasv[nt]};
            a = __builtin_amdgcn_mfma_f32_16x16x32_f16(a0[mt], Bf[nt][0], a, 0, 0, 0);
            a = __builtin_amdgcn_mfma_f32_16x16x32_f16(a1[mt], Bf[nt][1], a, 0, 0, 0);
            acc[nt] = a;
        }

        // restage: C[row16 = g*4+r][col = nt*16+c] -> Cbuf rows stride 68
        #pragma unroll
        for (int nt = 0; nt < 4; ++nt) {
            #pragma unroll
            for (int r = 0; r < 4; ++r)
                Cbuf[(g * 4 + r) * 68 + nt * 16 + c] = acc[nt][r];
        }
        __builtin_amdgcn_wave_barrier();

        // coalesced store: float4 idx f4 = i*64+lane of this 16-edge chunk
        const int e_chunk = base + w * 64 + mt * 16;
        float4* ob = reinterpret_cast<float4*>(out) + (size_t)e_chunk * 16;
        #pragma unroll
        for (int i = 0; i < 4; ++i) {
            int f4    = i * 64 + lane;
            int e_loc = f4 >> 4;
            int c4    = f4 & 15;
            if (e_chunk + e_loc < N) {
                float4 v = *reinterpret_cast<const float4*>(
                    &Cbuf[e_loc * 68 + c4 * 4]);
                ob[f4] = v;
            }
        }
        __builtin_amdgcn_wave_barrier();  // reads done before next mt overwrite
    }
}

extern "C" void kernel_launch(void* const* d_in, const int* in_sizes, int n_in,
                              void* d_out, int out_size, void* d_ws, size_t ws_size,
                              hipStream_t stream) {
    const float* env  = (const float*)d_in[0];
    const int*   idx  = (const int*)d_in[1];
    const float* Kmat = (const float*)d_in[2];
    const float* bias = (const float*)d_in[3];
    float* out = (float*)d_out;

    int N  = in_sizes[0] / 6;          // edges
    int n4 = in_sizes[1] / 4;          // pair_indices float4 count

    int nb_main = (N + 255) / 256;
    int nb_idx  = (n4 + 1023) / 1024;
    sph_edge_kernel<<<nb_main + nb_idx, 256, 0, stream>>>(
        env, (const int4*)idx, Kmat, bias, out, N, n4, nb_main);
}

// Round 10
// 128.745 us; speedup vs baseline: 1.7446x; 1.7446x over previous
//
#include <hip/hip_runtime.h>
#include <math.h>

#define FOURPI 12.566370614359172

typedef _Float16 f16x8 __attribute__((ext_vector_type(8)));
typedef float    f32x4 __attribute__((ext_vector_type(4)));

// R8 structure (proven 120.6us) + spill-safe LDS union:
//  - Ylds [256 rows][40 halves] = 20 KB, per-wave partitioned; NO
//    __syncthreads anywhere -> waves free-run (R8's win).
//  - REORDER: Bf/bias built AFTER the Y->LDS write, so Y[36] and Bf[32 regs]
//    are never live together (removes R9's spill at the (256,5) cap).
//  - Pre-read all 4 mt A-fragment pairs (A/B-neutral per R5/R6), then the
//    wave's Ylds slice is dead -> per-wave Cbuf [16][68] (4352 B) aliases
//    the wave's own 5120 B slice. Total LDS 20 KB.
//  - launch_bounds(256,5): 5 blocks/CU.
//  - Store path unchanged: MFMA -> Cbuf restage -> 1KB-contiguous float4
//    stores (64 lanes = 1 KB/instruction, full 128B lines).
__global__ __launch_bounds__(256, 5) void sph_edge_kernel(
    const float* __restrict__ env,    // [N,2,3]
    const float* __restrict__ Kmat,   // [36,64]
    const float* __restrict__ bias,   // [64]
    float* __restrict__ out,          // [N,64]
    int N)
{
    __shared__ __align__(16) _Float16 Ylds[256 * 40];   // 20 KB total

    const int tid  = threadIdx.x;
    const int lane = tid & 63;
    const int w    = tid >> 6;
    const int g    = lane >> 4;   // 16-lane group 0..3
    const int c    = lane & 15;
    const int base = blockIdx.x * 256;
    const int valid = (N - base < 256) ? (N - base) : 256;

    // per-wave Cbuf aliases the wave's own Ylds slice (4352 B of 5120 B)
    float* Cbuf = reinterpret_cast<float*>(&Ylds[w * 64 * 40]);

    // ---------------- Phase 1: geometry + Y[36] ----------------
    float Y[36];
    if (tid < valid) {
        const float* p6 = env + (size_t)(base + tid) * 6;
        float2 v0 = *reinterpret_cast<const float2*>(p6);
        float2 v1 = *reinterpret_cast<const float2*>(p6 + 2);
        float2 v2 = *reinterpret_cast<const float2*>(p6 + 4);
        float px = v0.x, py = v0.y, pz = v1.x;
        float ex = v1.y, ey = v2.x, ez = v2.y;

        float dot_t = px*ex + py*ey + pz*ez;
        float cxv = py*ez - pz*ey;
        float cyv = pz*ex - px*ez;
        float czv = px*ey - py*ex;
        float cr2 = cxv*cxv + cyv*cyv + czv*czv;
        float cross_t = sqrtf(cr2);
        float r = sqrtf(dot_t*dot_t + cr2);
        float x = 1.f, s = 0.f;               // cos(theta), sin(theta)
        if (r > 0.f) { x = dot_t / r; s = cross_t / r; }

        float dp = ez * x;
        float cp = fabsf(x) * cross_t;
        float rp = sqrtf(dp*dp + cp*cp);
        float c1 = 1.f, s1 = 0.f;             // cos(phi), sin(phi)
        if (rp > 0.f) { c1 = dp / rp; s1 = cp / rp; }

        float tc = 2.f * c1;
        float cm1 = c1,            sm1 = s1;
        float cm2 = tc*cm1 - 1.f,  sm2 = tc*sm1;
        float cm3 = tc*cm2 - cm1,  sm3 = tc*sm2 - sm1;
        float cm4 = tc*cm3 - cm2,  sm4 = tc*sm3 - sm2;
        float cm5 = tc*cm4 - cm3,  sm5 = tc*sm4 - sm3;

        float s2 = s*s, s3 = s2*s, s4 = s2*s2, s5 = s4*s;
        float P10 = x;
        float P11 = -s;
        float P20 = 1.5f*x*x - 0.5f;
        float P21 = -3.f*x*s;
        float P22 = 3.f*s2;
        float P30 = (5.f*x*P20 - 2.f*P10) * (1.f/3.f);
        float P31 = (5.f*x*P21 - 3.f*P11) * 0.5f;
        float P32 = 5.f*x*P22;
        float P33 = -15.f*s3;
        float P40 = (7.f*x*P30 - 3.f*P20) * 0.25f;
        float P41 = (7.f*x*P31 - 4.f*P21) * (1.f/3.f);
        float P42 = (7.f*x*P32 - 5.f*P22) * 0.5f;
        float P43 = 7.f*x*P33;
        float P44 = 105.f*s4;
        float P50 = (9.f*x*P40 - 4.f*P30) * 0.2f;
        float P51 = (9.f*x*P41 - 5.f*P31) * 0.25f;
        float P52 = (9.f*x*P42 - 6.f*P32) * (1.f/3.f);
        float P53 = (9.f*x*P43 - 7.f*P33) * 0.5f;
        float P54 = 9.f*x*P44;
        float P55 = -945.f*s5;

        const float SQ2 = 1.4142135623730951f;
        const float K00 = (float)sqrt(1.0/FOURPI);
        const float K10 = (float)sqrt(3.0/FOURPI);
        const float K11 = (float)sqrt(3.0/FOURPI/2.0);
        const float K20 = (float)sqrt(5.0/FOURPI);
        const float K21 = (float)sqrt(5.0/FOURPI/6.0);
        const float K22 = (float)sqrt(5.0/FOURPI/24.0);
        const float K30 = (float)sqrt(7.0/FOURPI);
        const float K31 = (float)sqrt(7.0/FOURPI/12.0);
        const float K32 = (float)sqrt(7.0/FOURPI/120.0);
        const float K33 = (float)sqrt(7.0/FOURPI/720.0);
        const float K40 = (float)sqrt(9.0/FOURPI);
        const float K41 = (float)sqrt(9.0/FOURPI/20.0);
        const float K42 = (float)sqrt(9.0/FOURPI/360.0);
        const float K43 = (float)sqrt(9.0/FOURPI/5040.0);
        const float K44 = (float)sqrt(9.0/FOURPI/40320.0);
        const float K50 = (float)sqrt(11.0/FOURPI);
        const float K51 = (float)sqrt(11.0/FOURPI/30.0);
        const float K52 = (float)sqrt(11.0/FOURPI/840.0);
        const float K53 = (float)sqrt(11.0/FOURPI/20160.0);
        const float K54 = (float)sqrt(11.0/FOURPI/362880.0);
        const float K55 = (float)sqrt(11.0/FOURPI/3628800.0);

        Y[0]  = K00;
        Y[1]  = SQ2*K11*sm1*P11;
        Y[2]  = K10*P10;
        Y[3]  = SQ2*K11*cm1*P11;
        Y[4]  = SQ2*K22*sm2*P22;
        Y[5]  = SQ2*K21*sm1*P21;
        Y[6]  = K20*P20;
        Y[7]  = SQ2*K21*cm1*P21;
        Y[8]  = SQ2*K22*cm2*P22;
        Y[9]  = SQ2*K33*sm3*P33;
        Y[10] = SQ2*K32*sm2*P32;
        Y[11] = SQ2*K31*sm1*P31;
        Y[12] = K30*P30;
        Y[13] = SQ2*K31*cm1*P31;
        Y[14] = SQ2*K32*cm2*P32;
        Y[15] = SQ2*K33*cm3*P33;
        Y[16] = SQ2*K44*sm4*P44;
        Y[17] = SQ2*K43*sm3*P43;
        Y[18] = SQ2*K42*sm2*P42;
        Y[19] = SQ2*K41*sm1*P41;
        Y[20] = K40*P40;
        Y[21] = SQ2*K41*cm1*P41;
        Y[22] = SQ2*K42*cm2*P42;
        Y[23] = SQ2*K43*cm3*P43;
        Y[24] = SQ2*K44*cm4*P44;
        Y[25] = SQ2*K55*sm5*P55;
        Y[26] = SQ2*K54*sm4*P54;
        Y[27] = SQ2*K53*sm3*P53;
        Y[28] = SQ2*K52*sm2*P52;
        Y[29] = SQ2*K51*sm1*P51;
        Y[30] = K50*P50;
        Y[31] = SQ2*K51*cm1*P51;
        Y[32] = SQ2*K52*cm2*P52;
        Y[33] = SQ2*K53*cm3*P53;
        Y[34] = SQ2*K54*cm4*P54;
        Y[35] = SQ2*K55*cm5*P55;
    } else {
        #pragma unroll
        for (int i = 0; i < 36; ++i) Y[i] = 0.f;
    }

    // write own row: 40 halves (36 data + 4 zeros), 5 x b128.  Y dies here.
    {
        _Float16 yh[40];
        #pragma unroll
        for (int i = 0; i < 36; ++i) yh[i] = (_Float16)Y[i];
        #pragma unroll
        for (int i = 36; i < 40; ++i) yh[i] = (_Float16)0.f;
        f16x8* yr = reinterpret_cast<f16x8*>(&Ylds[tid * 40]);
        #pragma unroll
        for (int s5 = 0; s5 < 5; ++s5)
            yr[s5] = *reinterpret_cast<const f16x8*>(&yh[s5 * 8]);
    }

    // ---- B fragments built AFTER Y is dead (keeps peak VGPR pressure low):
    //      lane holds B[k=kt*32+g*8+j][col=nt*16+c]; Kmat is 9KB, L1-hot.
    f16x8 Bf[4][2];
    #pragma unroll
    for (int nt = 0; nt < 4; ++nt) {
        #pragma unroll
        for (int kt = 0; kt < 2; ++kt) {
            #pragma unroll
            for (int j = 0; j < 8; ++j) {
                int k = kt * 32 + g * 8 + j;
                float v = (k < 36) ? Kmat[k * 64 + nt * 16 + c] : 0.f;
                Bf[nt][kt][j] = (_Float16)v;
            }
        }
    }
    float biasv[4];
    #pragma unroll
    for (int nt = 0; nt < 4; ++nt) biasv[nt] = bias[nt * 16 + c];

    // wave-local sync: rows [64w,64w+64) written/read only by wave w
    __builtin_amdgcn_wave_barrier();
    asm volatile("s_waitcnt lgkmcnt(0)" ::: "memory");
    __builtin_amdgcn_sched_barrier(0);

    // -------- pre-read ALL A-fragments (wave-local); Ylds slice then dead --
    f16x8 a0[4], a1[4];
    #pragma unroll
    for (int mt = 0; mt < 4; ++mt) {
        const int row = w * 64 + mt * 16 + c;
        a0[mt] = *reinterpret_cast<const f16x8*>(&Ylds[row * 40 + g * 8]);
        f16x8 t = {};
        if (g == 0)
            t = *reinterpret_cast<const f16x8*>(&Ylds[row * 40 + 32]);
        a1[mt] = t;
    }
    __builtin_amdgcn_wave_barrier();
    asm volatile("s_waitcnt lgkmcnt(0)" ::: "memory");
    __builtin_amdgcn_sched_barrier(0);

    // ---------------- Phase 2+3: MFMA per 16-edge tile, restage, store ----
    #pragma unroll
    for (int mt = 0; mt < 4; ++mt) {
        f32x4 acc[4];
        #pragma unroll
        for (int nt = 0; nt < 4; ++nt) {
            f32x4 a = {biasv[nt], biasv[nt], biasv[nt], biasv[nt]};
            a = __builtin_amdgcn_mfma_f32_16x16x32_f16(a0[mt], Bf[nt][0], a, 0, 0, 0);
            a = __builtin_amdgcn_mfma_f32_16x16x32_f16(a1[mt], Bf[nt][1], a, 0, 0, 0);
            acc[nt] = a;
        }

        // restage: C[row16 = g*4+r][col = nt*16+c] -> Cbuf rows stride 68
        #pragma unroll
        for (int nt = 0; nt < 4; ++nt) {
            #pragma unroll
            for (int r = 0; r < 4; ++r)
                Cbuf[(g * 4 + r) * 68 + nt * 16 + c] = acc[nt][r];
        }
        __builtin_amdgcn_wave_barrier();

        // coalesced store: float4 idx f4 = i*64+lane of this 16-edge chunk
        const int e_chunk = base + w * 64 + mt * 16;
        float4* ob = reinterpret_cast<float4*>(out) + (size_t)e_chunk * 16;
        #pragma unroll
        for (int i = 0; i < 4; ++i) {
            int f4    = i * 64 + lane;
            int e_loc = f4 >> 4;
            int c4    = f4 & 15;
            if (e_chunk + e_loc < N) {
                float4 v = *reinterpret_cast<const float4*>(
                    &Cbuf[e_loc * 68 + c4 * 4]);
                ob[f4] = v;
            }
        }
        __builtin_amdgcn_wave_barrier();  // reads done before next mt overwrite
    }
}

// pair_indices (int) -> float values appended after the [N,64] output
__global__ __launch_bounds__(256) void idx_copy_kernel(
    const int4* __restrict__ idx, float* __restrict__ outp, int n4)
{
    int i = blockIdx.x * 256 + threadIdx.x;
    if (i < n4) {
        int4 v = idx[i];
        float4 f = make_float4((float)v.x, (float)v.y, (float)v.z, (float)v.w);
        reinterpret_cast<float4*>(outp)[i] = f;
    }
}

extern "C" void kernel_launch(void* const* d_in, const int* in_sizes, int n_in,
                              void* d_out, int out_size, void* d_ws, size_t ws_size,
                              hipStream_t stream) {
    const float* env  = (const float*)d_in[0];
    const int*   idx  = (const int*)d_in[1];
    const float* Kmat = (const float*)d_in[2];
    const float* bias = (const float*)d_in[3];
    float* out = (float*)d_out;

    int N = in_sizes[0] / 6;          // edges
    int nidx = in_sizes[1];           // N*2

    int blocks = (N + 255) / 256;
    sph_edge_kernel<<<blocks, 256, 0, stream>>>(env, Kmat, bias, out, N);

    int n4 = nidx / 4;
    int iblocks = (n4 + 255) / 256;
    idx_copy_kernel<<<iblocks, 256, 0, stream>>>(
        (const int4*)idx, out + (size_t)N * 64, n4);
}

// Round 11
// 116.473 us; speedup vs baseline: 1.9284x; 1.1054x over previous
//
#include <hip/hip_runtime.h>
#include <math.h>

#define FOURPI 12.566370614359172

typedef _Float16 f16x8 __attribute__((ext_vector_type(8)));
typedef float    f32x4 __attribute__((ext_vector_type(4)));

// R8 structure (proven 120.6us) + idx-copy folded into LEADING blocks of the
// same grid (single dispatch; idx stores fill the store-free window while
// early main blocks run geometry).
//  - Ylds [256 rows][40 halves] = 20 KB, per-wave partitioned (wave w owns
//    rows [64w,64w+64)), NO __syncthreads -> waves free-run.
//  - Cbuf separate (NO union — R9/R10 showed union+(256,5) costs ~8us).
//  - launch_bounds(256,4); LDS 37.4 KB -> 4 blocks/CU.
//  - Store path: MFMA -> Cbuf restage -> 1KB-contiguous float4 stores
//    (64 lanes = 1 KB per instruction, full 128B lines).
__global__ __launch_bounds__(256, 4) void sph_edge_kernel(
    const float* __restrict__ env,    // [N,2,3]
    const int4*  __restrict__ idx4,   // pair_indices as int32 x4
    const float* __restrict__ Kmat,   // [36,64]
    const float* __restrict__ bias,   // [64]
    float* __restrict__ out,          // [N,64] floats, then [N,2] as float
    int N, int n4, int nb_idx)
{
    __shared__ __align__(16) _Float16 Ylds[256 * 40];   // 20 KB
    __shared__ __align__(16) float    Cbuf[4][16 * 68]; // 17.4 KB, per-wave

    const int tid = threadIdx.x;

    // ---------------- leading blocks: pair_indices copy ----------------
    if ((int)blockIdx.x < nb_idx) {
        float4* op = reinterpret_cast<float4*>(out + (size_t)N * 64);
        #pragma unroll
        for (int j = 0; j < 4; ++j) {
            int i4 = blockIdx.x * 1024 + j * 256 + tid;
            if (i4 < n4) {
                int4 v = idx4[i4];
                op[i4] = make_float4((float)v.x, (float)v.y,
                                     (float)v.z, (float)v.w);
            }
        }
        return;
    }

    const int lane = tid & 63;
    const int w    = tid >> 6;
    const int g    = lane >> 4;   // 16-lane group 0..3
    const int c    = lane & 15;
    const int base = (blockIdx.x - nb_idx) * 256;
    const int valid = (N - base < 256) ? (N - base) : 256;

    // ---- B fragments: lane holds B[k=kt*32+g*8+j][col=nt*16+c] ----
    f16x8 Bf[4][2];
    #pragma unroll
    for (int nt = 0; nt < 4; ++nt) {
        #pragma unroll
        for (int kt = 0; kt < 2; ++kt) {
            #pragma unroll
            for (int j = 0; j < 8; ++j) {
                int k = kt * 32 + g * 8 + j;
                float v = (k < 36) ? Kmat[k * 64 + nt * 16 + c] : 0.f;
                Bf[nt][kt][j] = (_Float16)v;
            }
        }
    }
    float biasv[4];
    #pragma unroll
    for (int nt = 0; nt < 4; ++nt) biasv[nt] = bias[nt * 16 + c];

    // ---------------- Phase 1: geometry + Y[36] ----------------
    float Y[36];
    if (tid < valid) {
        const float* p6 = env + (size_t)(base + tid) * 6;
        float2 v0 = *reinterpret_cast<const float2*>(p6);
        float2 v1 = *reinterpret_cast<const float2*>(p6 + 2);
        float2 v2 = *reinterpret_cast<const float2*>(p6 + 4);
        float px = v0.x, py = v0.y, pz = v1.x;
        float ex = v1.y, ey = v2.x, ez = v2.y;

        float dot_t = px*ex + py*ey + pz*ez;
        float cxv = py*ez - pz*ey;
        float cyv = pz*ex - px*ez;
        float czv = px*ey - py*ex;
        float cr2 = cxv*cxv + cyv*cyv + czv*czv;
        float cross_t = sqrtf(cr2);
        float r = sqrtf(dot_t*dot_t + cr2);
        float x = 1.f, s = 0.f;               // cos(theta), sin(theta)
        if (r > 0.f) { x = dot_t / r; s = cross_t / r; }

        float dp = ez * x;
        float cp = fabsf(x) * cross_t;
        float rp = sqrtf(dp*dp + cp*cp);
        float c1 = 1.f, s1 = 0.f;             // cos(phi), sin(phi)
        if (rp > 0.f) { c1 = dp / rp; s1 = cp / rp; }

        float tc = 2.f * c1;
        float cm1 = c1,            sm1 = s1;
        float cm2 = tc*cm1 - 1.f,  sm2 = tc*sm1;
        float cm3 = tc*cm2 - cm1,  sm3 = tc*sm2 - sm1;
        float cm4 = tc*cm3 - cm2,  sm4 = tc*sm3 - sm2;
        float cm5 = tc*cm4 - cm3,  sm5 = tc*sm4 - sm3;

        float s2 = s*s, s3 = s2*s, s4 = s2*s2, s5 = s4*s;
        float P10 = x;
        float P11 = -s;
        float P20 = 1.5f*x*x - 0.5f;
        float P21 = -3.f*x*s;
        float P22 = 3.f*s2;
        float P30 = (5.f*x*P20 - 2.f*P10) * (1.f/3.f);
        float P31 = (5.f*x*P21 - 3.f*P11) * 0.5f;
        float P32 = 5.f*x*P22;
        float P33 = -15.f*s3;
        float P40 = (7.f*x*P30 - 3.f*P20) * 0.25f;
        float P41 = (7.f*x*P31 - 4.f*P21) * (1.f/3.f);
        float P42 = (7.f*x*P32 - 5.f*P22) * 0.5f;
        float P43 = 7.f*x*P33;
        float P44 = 105.f*s4;
        float P50 = (9.f*x*P40 - 4.f*P30) * 0.2f;
        float P51 = (9.f*x*P41 - 5.f*P31) * 0.25f;
        float P52 = (9.f*x*P42 - 6.f*P32) * (1.f/3.f);
        float P53 = (9.f*x*P43 - 7.f*P33) * 0.5f;
        float P54 = 9.f*x*P44;
        float P55 = -945.f*s5;

        const float SQ2 = 1.4142135623730951f;
        const float K00 = (float)sqrt(1.0/FOURPI);
        const float K10 = (float)sqrt(3.0/FOURPI);
        const float K11 = (float)sqrt(3.0/FOURPI/2.0);
        const float K20 = (float)sqrt(5.0/FOURPI);
        const float K21 = (float)sqrt(5.0/FOURPI/6.0);
        const float K22 = (float)sqrt(5.0/FOURPI/24.0);
        const float K30 = (float)sqrt(7.0/FOURPI);
        const float K31 = (float)sqrt(7.0/FOURPI/12.0);
        const float K32 = (float)sqrt(7.0/FOURPI/120.0);
        const float K33 = (float)sqrt(7.0/FOURPI/720.0);
        const float K40 = (float)sqrt(9.0/FOURPI);
        const float K41 = (float)sqrt(9.0/FOURPI/20.0);
        const float K42 = (float)sqrt(9.0/FOURPI/360.0);
        const float K43 = (float)sqrt(9.0/FOURPI/5040.0);
        const float K44 = (float)sqrt(9.0/FOURPI/40320.0);
        const float K50 = (float)sqrt(11.0/FOURPI);
        const float K51 = (float)sqrt(11.0/FOURPI/30.0);
        const float K52 = (float)sqrt(11.0/FOURPI/840.0);
        const float K53 = (float)sqrt(11.0/FOURPI/20160.0);
        const float K54 = (float)sqrt(11.0/FOURPI/362880.0);
        const float K55 = (float)sqrt(11.0/FOURPI/3628800.0);

        Y[0]  = K00;
        Y[1]  = SQ2*K11*sm1*P11;
        Y[2]  = K10*P10;
        Y[3]  = SQ2*K11*cm1*P11;
        Y[4]  = SQ2*K22*sm2*P22;
        Y[5]  = SQ2*K21*sm1*P21;
        Y[6]  = K20*P20;
        Y[7]  = SQ2*K21*cm1*P21;
        Y[8]  = SQ2*K22*cm2*P22;
        Y[9]  = SQ2*K33*sm3*P33;
        Y[10] = SQ2*K32*sm2*P32;
        Y[11] = SQ2*K31*sm1*P31;
        Y[12] = K30*P30;
        Y[13] = SQ2*K31*cm1*P31;
        Y[14] = SQ2*K32*cm2*P32;
        Y[15] = SQ2*K33*cm3*P33;
        Y[16] = SQ2*K44*sm4*P44;
        Y[17] = SQ2*K43*sm3*P43;
        Y[18] = SQ2*K42*sm2*P42;
        Y[19] = SQ2*K41*sm1*P41;
        Y[20] = K40*P40;
        Y[21] = SQ2*K41*cm1*P41;
        Y[22] = SQ2*K42*cm2*P42;
        Y[23] = SQ2*K43*cm3*P43;
        Y[24] = SQ2*K44*cm4*P44;
        Y[25] = SQ2*K55*sm5*P55;
        Y[26] = SQ2*K54*sm4*P54;
        Y[27] = SQ2*K53*sm3*P53;
        Y[28] = SQ2*K52*sm2*P52;
        Y[29] = SQ2*K51*sm1*P51;
        Y[30] = K50*P50;
        Y[31] = SQ2*K51*cm1*P51;
        Y[32] = SQ2*K52*cm2*P52;
        Y[33] = SQ2*K53*cm3*P53;
        Y[34] = SQ2*K54*cm4*P54;
        Y[35] = SQ2*K55*cm5*P55;
    } else {
        #pragma unroll
        for (int i = 0; i < 36; ++i) Y[i] = 0.f;
    }

    // write own row: 40 halves (36 data + 4 zeros), 5 x b128
    {
        _Float16 yh[40];
        #pragma unroll
        for (int i = 0; i < 36; ++i) yh[i] = (_Float16)Y[i];
        #pragma unroll
        for (int i = 36; i < 40; ++i) yh[i] = (_Float16)0.f;
        f16x8* yr = reinterpret_cast<f16x8*>(&Ylds[tid * 40]);
        #pragma unroll
        for (int s5 = 0; s5 < 5; ++s5)
            yr[s5] = *reinterpret_cast<const f16x8*>(&yh[s5 * 8]);
    }
    // wave-local sync only: Ylds rows [64w,64w+64) are written and read
    // exclusively by wave w.  No __syncthreads -> waves free-run.
    __builtin_amdgcn_wave_barrier();
    asm volatile("s_waitcnt lgkmcnt(0)" ::: "memory");
    __builtin_amdgcn_sched_barrier(0);

    // ---------------- Phase 2+3: MFMA per 16-edge tile, restage, store ----
    #pragma unroll
    for (int mt = 0; mt < 4; ++mt) {
        const int row = w * 64 + mt * 16 + c;       // A-row for this lane
        f16x8 a0 = *reinterpret_cast<const f16x8*>(&Ylds[row * 40 + g * 8]);
        f16x8 a1 = {};
        if (g == 0)
            a1 = *reinterpret_cast<const f16x8*>(&Ylds[row * 40 + 32]);

        f32x4 acc[4];
        #pragma unroll
        for (int nt = 0; nt < 4; ++nt) {
            f32x4 a = {biasv[nt], biasv[nt], biasv[nt], biasv[nt]};
            a = __builtin_amdgcn_mfma_f32_16x16x32_f16(a0, Bf[nt][0], a, 0, 0, 0);
            a = __builtin_amdgcn_mfma_f32_16x16x32_f16(a1, Bf[nt][1], a, 0, 0, 0);
            acc[nt] = a;
        }

        // restage: C[row16 = g*4+r][col = nt*16+c] -> Cbuf rows stride 68
        #pragma unroll
        for (int nt = 0; nt < 4; ++nt) {
            #pragma unroll
            for (int r = 0; r < 4; ++r)
                Cbuf[w][(g * 4 + r) * 68 + nt * 16 + c] = acc[nt][r];
        }
        __builtin_amdgcn_wave_barrier();  // per-wave order (no cross-wave dep)

        // coalesced store: float4 idx f4 = i*64+lane of this 16-edge chunk
        const int e_chunk = base + w * 64 + mt * 16;
        float4* ob = reinterpret_cast<float4*>(out) + (size_t)e_chunk * 16;
        #pragma unroll
        for (int i = 0; i < 4; ++i) {
            int f4    = i * 64 + lane;
            int e_loc = f4 >> 4;
            int c4    = f4 & 15;
            if (e_chunk + e_loc < N) {
                float4 v = *reinterpret_cast<const float4*>(
                    &Cbuf[w][e_loc * 68 + c4 * 4]);
                ob[f4] = v;
            }
        }
        __builtin_amdgcn_wave_barrier();  // reads done before next mt overwrite
    }
}

extern "C" void kernel_launch(void* const* d_in, const int* in_sizes, int n_in,
                              void* d_out, int out_size, void* d_ws, size_t ws_size,
                              hipStream_t stream) {
    const float* env  = (const float*)d_in[0];
    const int*   idx  = (const int*)d_in[1];
    const float* Kmat = (const float*)d_in[2];
    const float* bias = (const float*)d_in[3];
    float* out = (float*)d_out;

    int N  = in_sizes[0] / 6;          // edges
    int n4 = in_sizes[1] / 4;          // pair_indices float4 count

    int nb_main = (N + 255) / 256;
    int nb_idx  = (n4 + 1023) / 1024;
    sph_edge_kernel<<<nb_idx + nb_main, 256, 0, stream>>>(
        env, (const int4*)idx, Kmat, bias, out, N, n4, nb_idx);
}